// Round 7
// baseline (2534.315 us; speedup 1.0000x reference)
//
#include <hip/hip_runtime.h>
#include <hip/hip_bf16.h>

#define NN 30000          // N_SPOT == N_USER
#define ATT_IN 512
#define HID 256

// gap-pad swizzle: insert a 4-float gap every 32 floats (keeps float4 alignment,
// maps 16 lanes' b128 reads onto >=8 distinct bank-quads -> <=2-way, free per m136)
#define GP(c) ((c) + 4 * ((c) >> 5))

// ---------------- degree count ----------------
__global__ __launch_bounds__(256) void k_count_deg(
    const int* __restrict__ us, const int* __restrict__ su, int E,
    int* __restrict__ d_us_s, int* __restrict__ d_us_d,
    int* __restrict__ d_su_s, int* __restrict__ d_su_d) {
  int e = blockIdx.x * 256 + threadIdx.x;
  if (e < E) {
    atomicAdd(&d_us_s[us[e]], 1);
    atomicAdd(&d_us_d[us[E + e]], 1);
    atomicAdd(&d_su_s[su[e]], 1);
    atomicAdd(&d_su_d[su[E + e]], 1);
  }
}

// ---------------- exclusive scan of n ints (single block) ----------------
__global__ __launch_bounds__(1024) void k_scan(
    const int* __restrict__ deg, int* __restrict__ rp, int n) {
  __shared__ int sums[1024];
  int t = threadIdx.x;
  int chunk = (n + 1023) / 1024;
  int lo = t * chunk, hi = lo + chunk;
  if (hi > n) hi = n;
  if (lo > n) lo = n;
  int s = 0;
  for (int i = lo; i < hi; ++i) s += deg[i];
  sums[t] = s;
  __syncthreads();
  for (int off = 1; off < 1024; off <<= 1) {
    int v = (t >= off) ? sums[t - off] : 0;
    __syncthreads();
    sums[t] += v;
    __syncthreads();
  }
  int run = sums[t] - s;  // exclusive prefix of my chunk
  for (int i = lo; i < hi; ++i) { rp[i] = run; run += deg[i]; }
  if (t == 1023) rp[n] = sums[1023];
}

// ---------------- CSR fill (by destination) ----------------
__global__ __launch_bounds__(256) void k_fill_csr(
    const int* __restrict__ src, const int* __restrict__ dst,
    const int* __restrict__ deg_s, const int* __restrict__ deg_d,
    const int* __restrict__ rp, int* __restrict__ fill,
    int* __restrict__ col, float* __restrict__ wv, int E) {
  int e = blockIdx.x * 256 + threadIdx.x;
  if (e < E) {
    int s = src[e], d = dst[e];
    int pos = rp[d] + atomicAdd(&fill[d], 1);
    col[pos] = s;
    wv[pos] = 1.0f / sqrtf((float)deg_s[s] * (float)deg_d[d]);
  }
}

// ---------------- wq[h][i] = sum_p W_att[h][i][p] * q[h][p] ----------------
__global__ __launch_bounds__(256) void k_wq(
    const float* __restrict__ W_att, const float* __restrict__ q_att,
    float* __restrict__ wq) {
  int g = blockIdx.x * 256 + threadIdx.x;
  if (g < 4 * ATT_IN) {
    int h = g >> 9, i = g & 511;
    const float* w = W_att + (size_t)h * ATT_IN * 128 + (size_t)i * 128;
    const float* q = q_att + h * 128;
    float s = 0.f;
    for (int p = 0; p < 128; ++p) s += w[p] * q[p];
    wq[g] = s;
  }
}

// ---------------- per-node attention weights (softmax over S=5) ----------------
// att[n][h][s], one wave per node
__global__ __launch_bounds__(256) void k_att(
    const float* __restrict__ x_spot, const float* __restrict__ wq,
    float* __restrict__ att) {
  int wave = threadIdx.x >> 6, lane = threadIdx.x & 63;
  int n = blockIdx.x * 4 + wave;
  // load wq fragment for my lane: wreg[h][0..7]
  float wreg[4][8];
  for (int h = 0; h < 4; ++h) {
    const float4* p = (const float4*)(wq + h * ATT_IN + lane * 8);
    float4 a = p[0], b = p[1];
    wreg[h][0] = a.x; wreg[h][1] = a.y; wreg[h][2] = a.z; wreg[h][3] = a.w;
    wreg[h][4] = b.x; wreg[h][5] = b.y; wreg[h][6] = b.z; wreg[h][7] = b.w;
  }
  float part[5][4];
  const float* xrow = x_spot + (size_t)n * (5 * ATT_IN);
  for (int s = 0; s < 5; ++s) {
    const float4* p = (const float4*)(xrow + s * ATT_IN + lane * 8);
    float4 a = p[0], b = p[1];
    float xv[8] = {a.x, a.y, a.z, a.w, b.x, b.y, b.z, b.w};
    for (int h = 0; h < 4; ++h) {
      float acc = 0.f;
      for (int i = 0; i < 8; ++i) acc += xv[i] * wreg[h][i];
      part[s][h] = acc;
    }
  }
  for (int off = 32; off; off >>= 1)
    for (int s = 0; s < 5; ++s)
      for (int h = 0; h < 4; ++h)
        part[s][h] += __shfl_xor(part[s][h], off);
  if (lane < 20) {
    int h = lane / 5, s = lane % 5;
    float l[5];
    for (int s2 = 0; s2 < 5; ++s2) {
      float v = part[s2][h];
      l[s2] = v > 0.f ? v : 0.2f * v;   // leaky_relu(0.2)
    }
    float m = l[0];
    for (int s2 = 1; s2 < 5; ++s2) m = fmaxf(m, l[s2]);
    float sum = 0.f;
    for (int s2 = 0; s2 < 5; ++s2) sum += expf(l[s2] - m);
    att[(size_t)n * 20 + h * 5 + s] = expf(l[s] - m) / sum;
  }
}

// ---------------- pooled projection v2: ALL 4 heads per block, x read ONCE --------
// Block: 32 nodes, 256 threads. xs0[n, h*128+c] = sum_k (sum_s att[h]*x[k]) * W[h][k][c]
#define PLANEA 584   // 16*36 + 8
#define PLANEB 2248  // 16*140 + 8
__global__ __launch_bounds__(256) void k_pooled2(
    const float* __restrict__ x_spot, const float* __restrict__ W_att,
    const float* __restrict__ att, float* __restrict__ xs0) {
  __shared__ float As[4 * PLANEA];
  __shared__ float Bs[4 * PLANEB];
  __shared__ float att_s[32][20];
  int t = threadIdx.x;
  int mb = blockIdx.x * 32;

  // stage att block: 32 nodes x 20 = 160 float4
  if (t < 160) {
    int m = t / 5, r4 = (t % 5) * 4;
    int n = mb + m;
    float4 v = make_float4(0.f, 0.f, 0.f, 0.f);
    if (n < NN) v = *(const float4*)&att[(size_t)n * 20 + r4];
    *(float4*)&att_s[m][r4] = v;
  }
  __syncthreads();

  // fill roles: thread handles (m=fm, k=fk) and (m=fm+16, k=fk)
  int fk = t & 15;
  int fm = t >> 4;
  float a5a[4][5], a5b[4][5];
  #pragma unroll
  for (int h = 0; h < 4; ++h)
    #pragma unroll
    for (int s = 0; s < 5; ++s) {
      a5a[h][s] = att_s[fm][h * 5 + s];
      a5b[h][s] = att_s[fm + 16][h * 5 + s];
    }
  int n_a = mb + fm, n_b = mb + fm + 16;
  bool va = n_a < NN, vb = n_b < NN;
  const float* xa = x_spot + (size_t)n_a * (5 * ATT_IN);
  const float* xb = x_spot + (size_t)n_b * (5 * ATT_IN);

  // compute roles: wave -> 8 nodes, lane -> (head, 8 cols)
  int wv_ = t >> 6;
  int h  = (t & 63) >> 4;
  int c0 = (t & 15) * 8;
  int p0 = GP(c0);
  int m0 = wv_ * 8;

  float acc[8][8];
  #pragma unroll
  for (int i = 0; i < 8; ++i)
    #pragma unroll
    for (int j = 0; j < 8; ++j) acc[i][j] = 0.f;

  for (int k0 = 0; k0 < ATT_IN; k0 += 16) {
    // ---- fill As: per-head weighted sum over s ----
    float xva[5], xvb[5];
    #pragma unroll
    for (int s = 0; s < 5; ++s) {
      xva[s] = va ? xa[s * ATT_IN + k0 + fk] : 0.f;
      xvb[s] = vb ? xb[s * ATT_IN + k0 + fk] : 0.f;
    }
    #pragma unroll
    for (int hh = 0; hh < 4; ++hh) {
      float sa = a5a[hh][0] * xva[0] + a5a[hh][1] * xva[1] + a5a[hh][2] * xva[2]
               + a5a[hh][3] * xva[3] + a5a[hh][4] * xva[4];
      float sb = a5b[hh][0] * xvb[0] + a5b[hh][1] * xvb[1] + a5b[hh][2] * xvb[2]
               + a5b[hh][3] * xvb[3] + a5b[hh][4] * xvb[4];
      As[hh * PLANEA + fk * 36 + fm]      = sa;
      As[hh * PLANEA + fk * 36 + fm + 16] = sb;
    }
    // ---- fill Bs: all heads' W[., k0..k0+15, .] ----
    #pragma unroll
    for (int r = 0; r < 8; ++r) {
      int flat = r * 256 + t;              // 0..2047
      int bh = flat >> 9, rem = flat & 511;
      int bk = rem >> 5, bc = (rem & 31) * 4;
      float4 w = *(const float4*)&W_att[(size_t)bh * ATT_IN * 128
                                        + (size_t)(k0 + bk) * 128 + bc];
      *(float4*)&Bs[bh * PLANEB + bk * 140 + GP(bc)] = w;
    }
    __syncthreads();
    // ---- inner product ----
    #pragma unroll
    for (int k = 0; k < 16; ++k) {
      float4 a0 = *(const float4*)&As[h * PLANEA + k * 36 + m0];
      float4 a1 = *(const float4*)&As[h * PLANEA + k * 36 + m0 + 4];
      float4 b0 = *(const float4*)&Bs[h * PLANEB + k * 140 + p0];
      float4 b1 = *(const float4*)&Bs[h * PLANEB + k * 140 + p0 + 4];
      float a[8] = {a0.x, a0.y, a0.z, a0.w, a1.x, a1.y, a1.z, a1.w};
      float b[8] = {b0.x, b0.y, b0.z, b0.w, b1.x, b1.y, b1.z, b1.w};
      #pragma unroll
      for (int i = 0; i < 8; ++i)
        #pragma unroll
        for (int j = 0; j < 8; ++j) acc[i][j] += a[i] * b[j];
    }
    __syncthreads();
  }
  #pragma unroll
  for (int i = 0; i < 8; ++i) {
    int n = mb + m0 + i;
    if (n < NN) {
      float4 o0 = {acc[i][0], acc[i][1], acc[i][2], acc[i][3]};
      float4 o1 = {acc[i][4], acc[i][5], acc[i][6], acc[i][7]};
      float* dst = xs0 + (size_t)n * ATT_IN + h * 128 + c0;
      *(float4*)dst = o0;
      *(float4*)(dst + 4) = o1;
    }
  }
}

// ---------------- f32 GEMM v2: C[M,N] = A[M,K] @ B[K,N] ----------------
// BM=128, BN=128, BK=16, 256 threads, 8x8 micro-tile, gap-padded LDS.
// Requires: K %16 == 0, N %128 == 0 (we call with N=256 only), full N-tiles.
__global__ __launch_bounds__(256) void k_gemm2(
    const float* __restrict__ A, const float* __restrict__ B,
    float* __restrict__ C, int M, int N, int K) {
  __shared__ float As[16 * 140];
  __shared__ float Bs[16 * 140];
  int mb = blockIdx.x * 128;
  int nb = blockIdx.y * 128;
  int t = threadIdx.x;
  int ty = t >> 4, tx = t & 15;         // compute: 8 rows x 8 cols
  int ka = t & 15, ma0 = (t >> 4) * 8;  // A fill: 8 scalars at k=ka
  int kb = t >> 4, nb0 = (t & 15) * 8;  // B fill: 2 float4 at k=kb
  int m0 = ty * 8, c0 = tx * 8;
  int pm0 = GP(m0), pc0 = GP(c0);
  int pa = ka * 140 + GP(ma0);
  int pb = kb * 140 + GP(nb0);

  float acc[8][8];
  #pragma unroll
  for (int i = 0; i < 8; ++i)
    #pragma unroll
    for (int j = 0; j < 8; ++j) acc[i][j] = 0.f;

  for (int k0 = 0; k0 < K; k0 += 16) {
    #pragma unroll
    for (int i = 0; i < 8; ++i) {
      int m = mb + ma0 + i;
      As[pa + i] = (m < M) ? A[(size_t)m * K + k0 + ka] : 0.f;
    }
    {
      float4 b0 = *(const float4*)&B[(size_t)(k0 + kb) * N + nb + nb0];
      float4 b1 = *(const float4*)&B[(size_t)(k0 + kb) * N + nb + nb0 + 4];
      *(float4*)&Bs[pb] = b0;
      *(float4*)&Bs[pb + 4] = b1;
    }
    __syncthreads();
    #pragma unroll
    for (int k = 0; k < 16; ++k) {
      float4 a0 = *(const float4*)&As[k * 140 + pm0];
      float4 a1 = *(const float4*)&As[k * 140 + pm0 + 4];
      float4 b0 = *(const float4*)&Bs[k * 140 + pc0];
      float4 b1 = *(const float4*)&Bs[k * 140 + pc0 + 4];
      float a[8] = {a0.x, a0.y, a0.z, a0.w, a1.x, a1.y, a1.z, a1.w};
      float b[8] = {b0.x, b0.y, b0.z, b0.w, b1.x, b1.y, b1.z, b1.w};
      #pragma unroll
      for (int i = 0; i < 8; ++i)
        #pragma unroll
        for (int j = 0; j < 8; ++j) acc[i][j] += a[i] * b[j];
    }
    __syncthreads();
  }
  #pragma unroll
  for (int i = 0; i < 8; ++i) {
    int m = mb + m0 + i;
    if (m < M) {
      float4 o0 = {acc[i][0], acc[i][1], acc[i][2], acc[i][3]};
      float4 o1 = {acc[i][4], acc[i][5], acc[i][6], acc[i][7]};
      float* dst = C + (size_t)m * N + nb + c0;
      *(float4*)dst = o0;
      *(float4*)(dst + 4) = o1;
    }
  }
}

// ---------------- CSR SpMM + relu + mean accumulate (+ output head) ----------------
// one wave per destination row; 64 lanes x float4 = 256 columns; j-loop unrolled x2
// mode 0: mean = val;  mode 1: mean += val;  mode 2: mean = (mean+val)/3, head out
__global__ __launch_bounds__(256) void k_spmm(
    const int* __restrict__ rp, const int* __restrict__ col,
    const float* __restrict__ wv, const float* __restrict__ tin,
    float* __restrict__ xout, float* __restrict__ meanout,
    const float* __restrict__ Wout, const float* __restrict__ bout,
    float* __restrict__ headout, int mode) {
  int wave = threadIdx.x >> 6, lane = threadIdx.x & 63;
  int n = blockIdx.x * 4 + wave;
  if (n >= NN) return;
  int j0 = rp[n], j1 = rp[n + 1];
  float ax = 0.f, ay = 0.f, az = 0.f, aw = 0.f;
  int j = j0;
  for (; j + 1 < j1; j += 2) {
    int s0 = col[j], s1 = col[j + 1];
    float w0 = wv[j], w1 = wv[j + 1];
    const float4 v0 = *(const float4*)&tin[(size_t)s0 * HID + lane * 4];
    const float4 v1 = *(const float4*)&tin[(size_t)s1 * HID + lane * 4];
    ax += w0 * v0.x + w1 * v1.x;
    ay += w0 * v0.y + w1 * v1.y;
    az += w0 * v0.z + w1 * v1.z;
    aw += w0 * v0.w + w1 * v1.w;
  }
  if (j < j1) {
    int s0 = col[j];
    float w0 = wv[j];
    const float4 v0 = *(const float4*)&tin[(size_t)s0 * HID + lane * 4];
    ax += w0 * v0.x; ay += w0 * v0.y; az += w0 * v0.z; aw += w0 * v0.w;
  }
  float4 val = {fmaxf(ax, 0.f), fmaxf(ay, 0.f), fmaxf(az, 0.f), fmaxf(aw, 0.f)};
  *(float4*)&xout[(size_t)n * HID + lane * 4] = val;
  float4* mp = (float4*)&meanout[(size_t)n * HID + lane * 4];
  if (mode == 0) {
    *mp = val;
  } else {
    float4 pm = *mp;
    pm.x += val.x; pm.y += val.y; pm.z += val.z; pm.w += val.w;
    if (mode == 2) {
      const float third = 1.f / 3.f;
      pm.x *= third; pm.y *= third; pm.z *= third; pm.w *= third;
    }
    *mp = pm;
  }
  if (mode == 2) {
    const float4 w4 = *(const float4*)&Wout[lane * 4];
    float d = val.x * w4.x + val.y * w4.y + val.z * w4.z + val.w * w4.w;
    for (int off = 32; off; off >>= 1) d += __shfl_xor(d, off);
    if (lane == 0) headout[n] = d + bout[0];
  }
}

extern "C" void kernel_launch(void* const* d_in, const int* in_sizes, int n_in,
                              void* d_out, int out_size, void* d_ws, size_t ws_size,
                              hipStream_t stream) {
  const float* x_spot  = (const float*)d_in[0];
  const float* x_user  = (const float*)d_in[1];
  const int*   edge_us = (const int*)d_in[2];
  const int*   edge_su = (const int*)d_in[3];
  const float* W_att   = (const float*)d_in[4];
  const float* q_att   = (const float*)d_in[5];
  const float* W0_us   = (const float*)d_in[6];
  const float* W0_su   = (const float*)d_in[7];
  const float* Wmid_us = (const float*)d_in[8];
  const float* Wmid_su = (const float*)d_in[9];
  const float* W_out_s = (const float*)d_in[10];
  const float* b_out_s = (const float*)d_in[11];
  const float* W_out_u = (const float*)d_in[12];
  const float* b_out_u = (const float*)d_in[13];

  const int E = in_sizes[2] / 2;  // 600000

  float* out_mean_s = (float*)d_out;                       // [30000,256]
  float* out_mean_u = out_mean_s + (size_t)NN * HID;       // [30000,256]
  float* out_s      = out_mean_u + (size_t)NN * HID;       // [30000]
  float* out_u      = out_s + NN;                          // [30000]

  // ---- workspace layout (4-byte units) — total ~33.97M elems ≈ 136 MB ----
  // xs/xu ALIAS the xs0 region: xs0 is dead after the layer-0 t_s GEMM,
  // which precedes the first k_spmm write to xs (stream-ordered).
  int*   wsI = (int*)d_ws;
  float* wsF = (float*)d_ws;
  int* deg_us_s = wsI + 0;
  int* deg_us_d = wsI + 30000;
  int* deg_su_s = wsI + 60000;
  int* deg_su_d = wsI + 90000;
  int* fill_s   = wsI + 120000;
  int* fill_u   = wsI + 150000;
  int* rp_s     = wsI + 180000;      // 30001 (pad to 30016)
  int* rp_u     = wsI + 210016;
  int* col_s    = wsI + 240032;      // E
  int* col_u    = wsI + 840032;
  float* wv_s   = wsF + 1440032;     // E
  float* wv_u   = wsF + 2040032;
  float* wq     = wsF + 2640032;     // 2048
  float* att    = wsF + 2642080;     // 30000*20
  float* xs0    = wsF + 3242080;     // 30000*512 (61.4 MB)
  float* xs     = wsF + 3242080;     // alias: first half of xs0
  float* xu     = wsF + 10922080;    // alias: second half of xs0
  float* t_u    = wsF + 18602080;    // 30000*256
  float* t_s    = wsF + 26282080;    // 30000*256; end = 33,962,080 floats

  const int EB = (E + 255) / 256;

  // zero degree + fill counters (workspace is poisoned 0xAA before every call)
  hipMemsetAsync(d_ws, 0, 180000 * sizeof(int), stream);

  // graph preprocessing
  k_count_deg<<<EB, 256, 0, stream>>>(edge_us, edge_su, E,
                                      deg_us_s, deg_us_d, deg_su_s, deg_su_d);
  k_scan<<<1, 1024, 0, stream>>>(deg_us_d, rp_s, NN);
  k_scan<<<1, 1024, 0, stream>>>(deg_su_d, rp_u, NN);
  k_fill_csr<<<EB, 256, 0, stream>>>(edge_us, edge_us + E, deg_us_s, deg_us_d,
                                     rp_s, fill_s, col_s, wv_s, E);
  k_fill_csr<<<EB, 256, 0, stream>>>(edge_su, edge_su + E, deg_su_s, deg_su_d,
                                     rp_u, fill_u, col_u, wv_u, E);

  // attention front-end
  k_wq<<<8, 256, 0, stream>>>(W_att, q_att, wq);
  k_att<<<NN / 4, 256, 0, stream>>>(x_spot, wq, att);
  k_pooled2<<<(NN + 31) / 32, 256, 0, stream>>>(x_spot, W_att, att, xs0);

  const int MB = (NN + 127) / 128;  // 235

  // layer 0 (K=512)
  k_gemm2<<<dim3(MB, 2), 256, 0, stream>>>(x_user, W0_us, t_u, NN, HID, 512);
  k_gemm2<<<dim3(MB, 2), 256, 0, stream>>>(xs0,    W0_su, t_s, NN, HID, 512);
  k_spmm<<<NN / 4, 256, 0, stream>>>(rp_s, col_s, wv_s, t_u, xs, out_mean_s,
                                     nullptr, nullptr, nullptr, 0);
  k_spmm<<<NN / 4, 256, 0, stream>>>(rp_u, col_u, wv_u, t_s, xu, out_mean_u,
                                     nullptr, nullptr, nullptr, 0);
  // layer 1 (K=256)
  k_gemm2<<<dim3(MB, 2), 256, 0, stream>>>(xu, Wmid_us,           t_u, NN, HID, HID);
  k_gemm2<<<dim3(MB, 2), 256, 0, stream>>>(xs, Wmid_su,           t_s, NN, HID, HID);
  k_spmm<<<NN / 4, 256, 0, stream>>>(rp_s, col_s, wv_s, t_u, xs, out_mean_s,
                                     nullptr, nullptr, nullptr, 1);
  k_spmm<<<NN / 4, 256, 0, stream>>>(rp_u, col_u, wv_u, t_s, xu, out_mean_u,
                                     nullptr, nullptr, nullptr, 1);
  // layer 2 (K=256) + heads + mean finalize
  k_gemm2<<<dim3(MB, 2), 256, 0, stream>>>(xu, Wmid_us + 256 * 256, t_u, NN, HID, HID);
  k_gemm2<<<dim3(MB, 2), 256, 0, stream>>>(xs, Wmid_su + 256 * 256, t_s, NN, HID, HID);
  k_spmm<<<NN / 4, 256, 0, stream>>>(rp_s, col_s, wv_s, t_u, xs, out_mean_s,
                                     W_out_s, b_out_s, out_s, 2);
  k_spmm<<<NN / 4, 256, 0, stream>>>(rp_u, col_u, wv_u, t_s, xu, out_mean_u,
                                     W_out_u, b_out_u, out_u, 2);
}